// Round 1
// baseline (44936.255 us; speedup 1.0000x reference)
//
#include <hip/hip_runtime.h>
#include <math.h>

#define T_STEPS 200

// ws layout (bytes)
#define XT_OFF   0ULL
#define XT_BYTES (200ULL*32*256*16)        // 26,214,400  : xT[t][c/4][b] float4
#define H0_OFF   (XT_OFF + XT_BYTES)
#define H0_BYTES (200ULL*128*256*16)       // 104,857,600 : h0[t][k/4][b] float4
#define H1_OFF   (H0_OFF + H0_BYTES)
#define H1_BYTES (2ULL*128*256*16)         // 1,048,576   : h1 ping-pong
#define CNT_OFF  (H1_OFF + H1_BYTES)       // 16 ints barrier counters

__device__ __forceinline__ float sigf(float x) { return 1.0f / (1.0f + expf(-x)); }

// proposals [b][t][c] -> xT[t][c/4][b] (float4 over c)
__global__ __launch_bounds__(256) void transpose_x(const float4* __restrict__ in,
                                                   float4* __restrict__ out) {
    const int t = blockIdx.x;      // 0..199
    const int b = threadIdx.x;     // 0..255
    #pragma unroll 4
    for (int cc = 0; cc < 32; ++cc) {
        out[((size_t)t * 32 + cc) * 256 + b] = in[((size_t)b * 200 + t) * 32 + cc];
    }
}

// Persistent LSTM scan for one layer.
// Grid: 256 blocks = 4 b-groups (64 batch each) x 64 g-groups (8 h-indices each).
// Block: 256 threads = 4 waves; wave w owns h-indices {g*8+w, g*8+w+4}; lane = batch.
// xv: [t][XC/4][256] float4.  hbuf: [slot][128][256] float4, slot = t & tmask.
__global__ __launch_bounds__(256) void lstm_scan(
    const float4* __restrict__ xv, const float* __restrict__ Wx,
    const float* __restrict__ Wr, const float* __restrict__ bih,
    const float* __restrict__ bhh, float4* hbuf,
    int XC, int tmask, int* cnt)
{
    const int tid   = threadIdx.x;
    const int wv    = tid >> 6;          // wave id 0..3
    const int bl    = tid & 63;
    const int b_grp = blockIdx.x >> 6;   // 0..3
    const int g_grp = blockIdx.x & 63;   // 0..63
    const int b     = b_grp * 64 + bl;
    // wave-uniform h-indices -> scalar (SGPR) weight addressing
    const int hid0 = __builtin_amdgcn_readfirstlane(g_grp * 8 + wv);
    const int hid1 = hid0 + 4;
    const int XC4  = XC >> 2;

    const float* wx0[4]; const float* wx1[4];
    const float* wr0[4]; const float* wr1[4];
    float bs0[4], bs1[4];
    #pragma unroll
    for (int q = 0; q < 4; ++q) {
        const int r0 = q * 512 + hid0;
        const int r1 = q * 512 + hid1;
        wx0[q] = Wx + (size_t)r0 * XC;   wx1[q] = Wx + (size_t)r1 * XC;
        wr0[q] = Wr + (size_t)r0 * 512;  wr1[q] = Wr + (size_t)r1 * 512;
        bs0[q] = bih[r0] + bhh[r0];
        bs1[q] = bih[r1] + bhh[r1];
    }

    float c0 = 0.f, c1 = 0.f;
    float* hw = (float*)hbuf;

    for (int t = 0; t < T_STEPS; ++t) {
        float a0[4], a1[4];
        #pragma unroll
        for (int q = 0; q < 4; ++q) { a0[q] = bs0[q]; a1[q] = bs1[q]; }

        // input-projection part: v = x_t[b][:]
        const float4* xp = xv + (size_t)t * XC4 * 256 + b;
        #pragma unroll 2
        for (int k4 = 0; k4 < XC4; ++k4) {
            const float4 v = xp[(size_t)k4 * 256];
            #pragma unroll
            for (int q = 0; q < 4; ++q) {
                const float4 w = *(const float4*)(wx0[q] + (k4 << 2));
                a0[q] += w.x*v.x + w.y*v.y + w.z*v.z + w.w*v.w;
                const float4 u = *(const float4*)(wx1[q] + (k4 << 2));
                a1[q] += u.x*v.x + u.y*v.y + u.z*v.z + u.w*v.w;
            }
        }
        // recurrent part: v = h_{t-1}[b][:]
        if (t > 0) {
            const float4* hp = hbuf + (size_t)((t - 1) & tmask) * 128 * 256 + b;
            #pragma unroll 2
            for (int kk = 0; kk < 128; ++kk) {
                const float4 v = hp[(size_t)kk * 256];
                #pragma unroll
                for (int q = 0; q < 4; ++q) {
                    const float4 w = *(const float4*)(wr0[q] + (kk << 2));
                    a0[q] += w.x*v.x + w.y*v.y + w.z*v.z + w.w*v.w;
                    const float4 u = *(const float4*)(wr1[q] + (kk << 2));
                    a1[q] += u.x*v.x + u.y*v.y + u.z*v.z + u.w*v.w;
                }
            }
        }

        const int slot = t & tmask;
        {
            const float ig = sigf(a0[0]), fg = sigf(a0[1]);
            const float gg = tanhf(a0[2]), og = sigf(a0[3]);
            c0 = fg * c0 + ig * gg;
            const float h = og * tanhf(c0);
            hw[(((size_t)slot * 128 + (hid0 >> 2)) * 256 + b) * 4 + (hid0 & 3)] = h;
        }
        {
            const float ig = sigf(a1[0]), fg = sigf(a1[1]);
            const float gg = tanhf(a1[2]), og = sigf(a1[3]);
            c1 = fg * c1 + ig * gg;
            const float h = og * tanhf(c1);
            hw[(((size_t)slot * 128 + (hid1 >> 2)) * 256 + b) * 4 + (hid1 & 3)] = h;
        }

        // inter-block barrier among the 64 blocks of this batch group
        __threadfence();
        __syncthreads();
        if (tid == 0) {
            __hip_atomic_fetch_add(cnt + b_grp, 1, __ATOMIC_RELEASE, __HIP_MEMORY_SCOPE_AGENT);
            const int target = 64 * (t + 1);
            while (__hip_atomic_load(cnt + b_grp, __ATOMIC_ACQUIRE, __HIP_MEMORY_SCOPE_AGENT) < target) {}
        }
        __syncthreads();
        __threadfence();
    }
}

// heads: base[k][b] (float4 over k) -> cls (256x40), bbox (256x2), 2 zero scalars
__global__ __launch_bounds__(64) void heads(
    const float4* __restrict__ base, const float4* __restrict__ clsW,
    const float* __restrict__ clsb, const float4* __restrict__ bbW,
    const float* __restrict__ bbb, float* __restrict__ out)
{
    const int b = blockIdx.x;    // 0..255
    const int j = threadIdx.x;   // 0..63
    if (j < 42) {
        const float4* w = (j < 40) ? (clsW + (size_t)j * 128) : (bbW + (size_t)(j - 40) * 128);
        float acc = 0.f;
        #pragma unroll 4
        for (int kk = 0; kk < 128; ++kk) {
            const float4 bv = base[(size_t)kk * 256 + b];
            const float4 wv = w[kk];
            acc += bv.x*wv.x + bv.y*wv.y + bv.z*wv.z + bv.w*wv.w;
        }
        if (j < 40) out[(size_t)b * 40 + j] = acc + clsb[j];
        else        out[10240 + (size_t)b * 2 + (j - 40)] = acc + bbb[j - 40];
    }
    if (b == 0 && (j == 62 || j == 63)) out[10752 + (j - 62)] = 0.f;
}

extern "C" void kernel_launch(void* const* d_in, const int* in_sizes, int n_in,
                              void* d_out, int out_size, void* d_ws, size_t ws_size,
                              hipStream_t stream) {
    const float* proposals = (const float*)d_in[2];
    const float* Wih0 = (const float*)d_in[4];
    const float* Whh0 = (const float*)d_in[5];
    const float* bih0 = (const float*)d_in[6];
    const float* bhh0 = (const float*)d_in[7];
    const float* Wih1 = (const float*)d_in[8];
    const float* Whh1 = (const float*)d_in[9];
    const float* bih1 = (const float*)d_in[10];
    const float* bhh1 = (const float*)d_in[11];
    const float* clsW = (const float*)d_in[12];
    const float* clsb = (const float*)d_in[13];
    const float* bbW  = (const float*)d_in[14];
    const float* bbb  = (const float*)d_in[15];

    float4* xT = (float4*)((char*)d_ws + XT_OFF);
    float4* h0 = (float4*)((char*)d_ws + H0_OFF);
    float4* h1 = (float4*)((char*)d_ws + H1_OFF);
    int*   cnt = (int*)((char*)d_ws + CNT_OFF);

    hipMemsetAsync(cnt, 0, 64, stream);

    transpose_x<<<200, 256, 0, stream>>>((const float4*)proposals, xT);

    // layer 0: XC=128, h stored per-t (tmask=255 keeps t as-is for t<200)
    lstm_scan<<<256, 256, 0, stream>>>(xT, Wih0, Whh0, bih0, bhh0, h0, 128, 255, cnt);
    // layer 1: input is h0 (same layout, XC=512), h ping-pong (tmask=1)
    lstm_scan<<<256, 256, 0, stream>>>((const float4*)h0, Wih1, Whh1, bih1, bhh1, h1, 512, 1, cnt + 4);

    // base_feat = h1 slot (199 & 1) = 1
    heads<<<256, 64, 0, stream>>>((const float4*)(h1 + 128 * 256), (const float4*)clsW,
                                  clsb, (const float4*)bbW, bbb, (float*)d_out);
}

// Round 2
// 33339.819 us; speedup vs baseline: 1.3478x; 1.3478x over previous
//
#include <hip/hip_runtime.h>
#include <math.h>

#define T_ALL 200
#define G     2048
#define H     512

typedef __attribute__((address_space(1))) const unsigned int g_u32;
typedef __attribute__((address_space(3))) unsigned int l_u32;

__device__ __forceinline__ void gl2lds16(const void* g, void* l) {
    __builtin_amdgcn_global_load_lds((g_u32*)g, (l_u32*)l, 16, 0, 0);
}

__device__ __forceinline__ float sigf(float x) { return 1.0f / (1.0f + expf(-x)); }

// proposals [b][t][c] -> xT[t][c/4][b] (float4 over c)
__global__ __launch_bounds__(256) void transpose_x(const float4* __restrict__ in,
                                                   float4* __restrict__ out) {
    const int t = blockIdx.x;      // 0..199
    const int b = threadIdx.x;     // 0..255
    #pragma unroll 4
    for (int cc = 0; cc < 32; ++cc) {
        out[((size_t)t * 32 + cc) * 256 + b] = in[((size_t)b * 200 + t) * 32 + cc];
    }
}

// xp[tloc][r][b] = bih[r]+bhh[r] + sum_k W[r][k] * x[t][k][b]
// x layout: [t][K4][256] float4 (float4 spans k). grid (len, 4 bg, 64 rchunks), block 256.
// Wave owns 8 consecutive rows (wave-uniform -> scalar weight loads); lane = batch.
__global__ __launch_bounds__(256) void xproj_gemm(
    const float4* __restrict__ x, const float* __restrict__ W,
    const float* __restrict__ bih, const float* __restrict__ bhh,
    float* __restrict__ xp, int K4, int t0)
{
    __shared__ float4 hs[2][2048];   // 2 x 32 KB
    const int tloc = blockIdx.x;
    const int t    = t0 + tloc;
    const int bg   = blockIdx.y;
    const int tid  = threadIdx.x;
    const int wv   = tid >> 6;
    const int lane = tid & 63;
    const int bG   = bg * 64 + lane;
    const int rbase = __builtin_amdgcn_readfirstlane(blockIdx.z * 32 + wv * 8);

    const float* wr[8];
    float a[8];
    #pragma unroll
    for (int i = 0; i < 8; ++i) {
        const int r = rbase + i;
        wr[i] = W + (size_t)r * (K4 * 4);
        a[i] = bih[r] + bhh[r];
    }

    const float4* xt = x + (size_t)t * K4 * 256;
    const int nr = K4 >> 5;   // 1 (K=128) or 4 (K=512)

    #pragma unroll
    for (int j = 0; j < 8; ++j) {
        const int kk = wv + 4 * j;
        gl2lds16(xt + (size_t)kk * 256 + bG, &hs[0][kk * 64]);
    }
    __syncthreads();

    for (int ro = 0; ro < nr; ++ro) {
        if (ro + 1 < nr) {
            #pragma unroll
            for (int j = 0; j < 8; ++j) {
                const int kk = wv + 4 * j;
                gl2lds16(xt + (size_t)((ro + 1) * 32 + kk) * 256 + bG,
                         &hs[(ro + 1) & 1][kk * 64]);
            }
        }
        const float4* hb = hs[ro & 1];
        const int kbase = ro * 32;
        #pragma unroll 4
        for (int kk = 0; kk < 32; ++kk) {
            const float4 v = hb[kk * 64 + lane];
            const int ko = (kbase + kk) * 4;
            #pragma unroll
            for (int i = 0; i < 8; ++i) {
                const float4 w = *(const float4*)(wr[i] + ko);
                a[i] += w.x * v.x + w.y * v.y + w.z * v.z + w.w * v.w;
            }
        }
        __syncthreads();
    }

    #pragma unroll
    for (int i = 0; i < 8; ++i)
        xp[((size_t)tloc * G + rbase + i) * 256 + bG] = a[i];
}

// Recurrent-only LSTM scan. grid (64, 4 bgroups), block 256 = 4 waves.
// Wave owns hid pair {bi*8+2w, +1}; thread owns the 4 gates of each hid (8 rows,
// all wave-uniform -> scalar weight loads). lane = batch within the 64-batch group.
// h stored [slot][k/4][256b] float4-over-k at hbase + slot*32768.
__global__ __launch_bounds__(256) void lstm_scan(
    const float* __restrict__ xp, const float* __restrict__ Wr,
    float4* hbase, float* __restrict__ cbuf,
    int t0, int t1, int tmask, int* cnt)
{
    __shared__ float4 hs[2][2048];   // 2 x 32 KB double buffer
    const int tid  = threadIdx.x;
    const int wv   = tid >> 6;
    const int lane = tid & 63;
    const int bi   = blockIdx.x;     // 0..63
    const int bg   = blockIdx.y;     // 0..3
    const int bG   = bg * 64 + lane;
    const int hid0 = __builtin_amdgcn_readfirstlane(bi * 8 + wv * 2);

    const float* wr[8];
    #pragma unroll
    for (int p = 0; p < 2; ++p)
        #pragma unroll
        for (int q = 0; q < 4; ++q)
            wr[p * 4 + q] = Wr + (size_t)(q * H + hid0 + p) * H;

    float c0, c1;
    if (t0 > 0) {
        c0 = cbuf[(size_t)hid0 * 256 + bG];
        c1 = cbuf[(size_t)(hid0 + 1) * 256 + bG];
    } else { c0 = 0.f; c1 = 0.f; }

    for (int t = t0; t < t1; ++t) {
        float a[8];
        const float* xpt = xp + (size_t)(t - t0) * G * 256;
        #pragma unroll
        for (int p = 0; p < 2; ++p)
            #pragma unroll
            for (int q = 0; q < 4; ++q)
                a[p * 4 + q] = xpt[(size_t)(q * H + hid0 + p) * 256 + bG];

        if (t > 0) {
            const float4* hin = hbase + (size_t)((t - 1) & tmask) * 32768;
            #pragma unroll
            for (int j = 0; j < 8; ++j) {
                const int kk = wv + 4 * j;
                gl2lds16(hin + (size_t)kk * 256 + bG, &hs[0][kk * 64]);
            }
            __syncthreads();
            for (int ro = 0; ro < 4; ++ro) {
                if (ro < 3) {
                    #pragma unroll
                    for (int j = 0; j < 8; ++j) {
                        const int kk = wv + 4 * j;
                        gl2lds16(hin + (size_t)((ro + 1) * 32 + kk) * 256 + bG,
                                 &hs[(ro + 1) & 1][kk * 64]);
                    }
                }
                const float4* hb = hs[ro & 1];
                const int kbase = ro * 32;
                #pragma unroll 4
                for (int kk = 0; kk < 32; ++kk) {
                    const float4 v = hb[kk * 64 + lane];
                    const int ko = (kbase + kk) * 4;
                    #pragma unroll
                    for (int i = 0; i < 8; ++i) {
                        const float4 w = *(const float4*)(wr[i] + ko);
                        a[i] += w.x * v.x + w.y * v.y + w.z * v.z + w.w * v.w;
                    }
                }
                __syncthreads();
            }
        }

        const int slot = t & tmask;
        float* hw = (float*)(hbase + (size_t)slot * 32768);
        {
            const float ig = sigf(a[0]), fg = sigf(a[1]);
            const float gg = tanhf(a[2]), og = sigf(a[3]);
            c0 = fg * c0 + ig * gg;
            const float h = og * tanhf(c0);
            hw[(((hid0 >> 2) * 256) + bG) * 4 + (hid0 & 3)] = h;
        }
        {
            const float ig = sigf(a[4]), fg = sigf(a[5]);
            const float gg = tanhf(a[6]), og = sigf(a[7]);
            c1 = fg * c1 + ig * gg;
            const float h = og * tanhf(c1);
            const int h1i = hid0 + 1;
            hw[(((h1i >> 2) * 256) + bG) * 4 + (h1i & 3)] = h;
        }

        __threadfence();
        __syncthreads();
        if (tid == 0) {
            __hip_atomic_fetch_add(cnt + bg, 1, __ATOMIC_RELEASE, __HIP_MEMORY_SCOPE_AGENT);
            const int target = 64 * (t + 1);
            while (__hip_atomic_load(cnt + bg, __ATOMIC_ACQUIRE, __HIP_MEMORY_SCOPE_AGENT) < target) {}
        }
        __syncthreads();
    }

    cbuf[(size_t)hid0 * 256 + bG] = c0;
    cbuf[(size_t)(hid0 + 1) * 256 + bG] = c1;
}

// heads: base[k/4][b] (float4 over k) -> cls (256x40), bbox (256x2), 2 zero scalars
__global__ __launch_bounds__(64) void heads(
    const float4* __restrict__ base, const float4* __restrict__ clsW,
    const float* __restrict__ clsb, const float4* __restrict__ bbW,
    const float* __restrict__ bbb, float* __restrict__ out)
{
    const int b = blockIdx.x;    // 0..255
    const int j = threadIdx.x;   // 0..63
    if (j < 42) {
        const float4* w = (j < 40) ? (clsW + (size_t)j * 128) : (bbW + (size_t)(j - 40) * 128);
        float acc = 0.f;
        #pragma unroll 4
        for (int kk = 0; kk < 128; ++kk) {
            const float4 bv = base[(size_t)kk * 256 + b];
            const float4 wv = w[kk];
            acc += bv.x*wv.x + bv.y*wv.y + bv.z*wv.z + bv.w*wv.w;
        }
        if (j < 40) out[(size_t)b * 40 + j] = acc + clsb[j];
        else        out[10240 + (size_t)b * 2 + (j - 40)] = acc + bbb[j - 40];
    }
    if (b == 0 && (j == 62 || j == 63)) out[10752 + (j - 62)] = 0.f;
}

extern "C" void kernel_launch(void* const* d_in, const int* in_sizes, int n_in,
                              void* d_out, int out_size, void* d_ws, size_t ws_size,
                              hipStream_t stream) {
    const float* proposals = (const float*)d_in[2];
    const float* Wih0 = (const float*)d_in[4];
    const float* Whh0 = (const float*)d_in[5];
    const float* bih0 = (const float*)d_in[6];
    const float* bhh0 = (const float*)d_in[7];
    const float* Wih1 = (const float*)d_in[8];
    const float* Whh1 = (const float*)d_in[9];
    const float* bih1 = (const float*)d_in[10];
    const float* bhh1 = (const float*)d_in[11];
    const float* clsW = (const float*)d_in[12];
    const float* clsb = (const float*)d_in[13];
    const float* bbW  = (const float*)d_in[14];
    const float* bbb  = (const float*)d_in[15];

    char* ws = (char*)d_ws;
    const size_t XT_B  = 200ull * 32 * 256 * 16;    // 26,214,400
    const size_t H0_B  = 200ull * 128 * 256 * 16;   // 104,857,600
    const size_t H1_B  = 2ull * 128 * 256 * 16;     // 1,048,576
    const size_t C_B   = 512ull * 256 * 4;          // 524,288 each
    const size_t CNT_B = 256;
    const size_t fixed = XT_B + H0_B + H1_B + 2 * C_B + CNT_B;
    const size_t xp_per_t = (size_t)G * 256 * 4;    // 2,097,152 per timestep

    size_t xp_avail = (ws_size > fixed) ? (ws_size - fixed) : 0;
    int TC = (int)(xp_avail / xp_per_t);
    if (TC > 200) TC = 200;
    if (TC < 1) TC = 1;

    float4* xT = (float4*)ws;
    float4* h0 = (float4*)(ws + XT_B);
    float4* h1 = (float4*)(ws + XT_B + H0_B);
    float*  c0 = (float*)(ws + XT_B + H0_B + H1_B);
    float*  c1 = (float*)(ws + XT_B + H0_B + H1_B + C_B);
    int*   cnt = (int*)(ws + XT_B + H0_B + H1_B + 2 * C_B);
    float*  xp = (float*)(ws + fixed);

    hipMemsetAsync(cnt, 0, CNT_B, stream);

    transpose_x<<<200, 256, 0, stream>>>((const float4*)proposals, xT);

    // layer 0: x = xT (K=128), h -> h0 (per-t slots, tmask=255)
    for (int t0 = 0; t0 < T_ALL; t0 += TC) {
        const int len = (TC < T_ALL - t0) ? TC : (T_ALL - t0);
        xproj_gemm<<<dim3(len, 4, 64), 256, 0, stream>>>(xT, Wih0, bih0, bhh0, xp, 32, t0);
        lstm_scan<<<dim3(64, 4), 256, 0, stream>>>(xp, Whh0, h0, c0, t0, t0 + len, 255, cnt);
    }
    // layer 1: x = h0 (K=512), h -> h1 ping-pong (tmask=1)
    for (int t0 = 0; t0 < T_ALL; t0 += TC) {
        const int len = (TC < T_ALL - t0) ? TC : (T_ALL - t0);
        xproj_gemm<<<dim3(len, 4, 64), 256, 0, stream>>>((const float4*)h0, Wih1, bih1, bhh1, xp, 128, t0);
        lstm_scan<<<dim3(64, 4), 256, 0, stream>>>(xp, Whh1, h1, c1, t0, t0 + len, 1, cnt + 4);
    }

    // base_feat = h1 slot (199 & 1) = 1
    heads<<<256, 64, 0, stream>>>((const float4*)(h1 + 32768), (const float4*)clsW,
                                  clsb, (const float4*)bbW, bbb, (float*)d_out);
}